// Round 13
// baseline (478.574 us; speedup 1.0000x reference)
//
#include <hip/hip_runtime.h>
#include <cstdint>
#include <cstddef>

#define DEV __device__ __forceinline__

typedef __bf16 bf16x8 __attribute__((ext_vector_type(8)));
typedef float f32x4 __attribute__((ext_vector_type(4)));
typedef unsigned short u16;
typedef unsigned int u32;

constexpr int Bq = 4, Tq = 2048, Dq = 2048, Kq = 7, DB = 128, TK = 16;
constexpr float SD = 0.08838834764831845f;          // 1/sqrt(128)
constexpr float PHIc = 1.618033988749895f;
constexpr float PSIc = -0.6180339887498949f;
constexpr float DPHI = 2.2360679774997896f;          // PHI - PSI = sqrt(5)
#define NEG_INF (-__builtin_inff())

DEV u16 f2bf(float f) {
  union { float f; u32 u; } x; x.f = f;
  u32 r = (x.u + 0x7fffu + ((x.u >> 16) & 1u)) >> 16;
  return (u16)r;
}
DEV float bfbits2f(u32 h) { union { u32 u; float f; } x; x.u = h << 16; return x.f; }

DEV void async16(void* l, const void* g) {
  __builtin_amdgcn_global_load_lds((const __attribute__((address_space(1))) void*)g,
                                   (__attribute__((address_space(3))) void*)l, 16, 0, 0);
}

// ---------------- fused prep: W0->bf16  |  LN rows -> bf16  |  qmean stage 1 ----------------
__global__ __launch_bounds__(256) void k_prep(const float* __restrict__ W0, u16* __restrict__ W0b,
                                              const float* __restrict__ Xw, const float* __restrict__ g,
                                              const float* __restrict__ bb, u16* __restrict__ Xn,
                                              const float* __restrict__ Xr, float* __restrict__ part) {
  int bid = blockIdx.x;
  int tid = threadIdx.x;
  if (bid < 2048) {
    size_t i = ((size_t)bid * 256 + tid) * 8;
    float4 a = *(const float4*)&W0[i];
    float4 c = *(const float4*)&W0[i + 4];
    u32 p0 = (u32)f2bf(a.x) | ((u32)f2bf(a.y) << 16);
    u32 p1 = (u32)f2bf(a.z) | ((u32)f2bf(a.w) << 16);
    u32 p2 = (u32)f2bf(c.x) | ((u32)f2bf(c.y) << 16);
    u32 p3 = (u32)f2bf(c.z) | ((u32)f2bf(c.w) << 16);
    uint4 st; st.x = p0; st.y = p1; st.z = p2; st.w = p3;
    *(uint4*)&W0b[i] = st;
  } else if (bid < 2048 + 8192) {
    int row = bid - 2048;
    const float* xr = Xw + (size_t)row * Dq;
    int lane = tid & 63, w = tid >> 6;
    float4 a = *(const float4*)&xr[tid * 8];
    float4 c = *(const float4*)&xr[tid * 8 + 4];
    float s = a.x + a.y + a.z + a.w + c.x + c.y + c.z + c.w;
    float q = a.x*a.x + a.y*a.y + a.z*a.z + a.w*a.w + c.x*c.x + c.y*c.y + c.z*c.z + c.w*c.w;
    #pragma unroll
    for (int o = 32; o; o >>= 1) { s += __shfl_xor(s, o); q += __shfl_xor(q, o); }
    __shared__ float red[8];
    if (lane == 0) { red[w] = s; red[w + 4] = q; }
    __syncthreads();
    float S = red[0] + red[1] + red[2] + red[3];
    float Q = red[4] + red[5] + red[6] + red[7];
    float mean = S * (1.0f / Dq);
    float var = Q * (1.0f / Dq) - mean * mean;
    float rstd = rsqrtf(var + 1e-5f);
    float v[8] = {a.x, a.y, a.z, a.w, c.x, c.y, c.z, c.w};
    u32 p[4];
    #pragma unroll
    for (int j = 0; j < 4; ++j) {
      int d0 = tid * 8 + j * 2;
      float o0 = (v[j*2]   - mean) * rstd * g[d0]   + bb[d0];
      float o1 = (v[j*2+1] - mean) * rstd * g[d0+1] + bb[d0+1];
      p[j] = (u32)f2bf(o0) | ((u32)f2bf(o1) << 16);
    }
    uint4 st; st.x = p[0]; st.y = p[1]; st.z = p[2]; st.w = p[3];
    *(uint4*)&Xn[(size_t)row * Dq + tid * 8] = st;
  } else {
    int f = bid - (2048 + 8192);
    int s = f & 1, y = (f >> 1) & 31, b = f >> 6;
    const float* xb = Xr + (size_t)b * Tq * Dq + (size_t)s * 1024 + tid * 4;
    f32x4 acc = {0.f, 0.f, 0.f, 0.f};
    #pragma unroll 4
    for (int t = 0; t < 64; ++t) {
      const float4 v = *(const float4*)&xb[(size_t)(y * 64 + t) * Dq];
      acc[0] += v.x; acc[1] += v.y; acc[2] += v.z; acc[3] += v.w;
    }
    float4 st; st.x = acc[0]; st.y = acc[1]; st.z = acc[2]; st.w = acc[3];
    *(float4*)&part[((size_t)(b * 32 + y)) * Dq + s * 1024 + tid * 4] = st;
  }
}

// ---------------- big GEMM (T2 swizzle) + embedded qmean2 (y==16) ----------------
__global__ __launch_bounds__(256) void k_gemm(const u16* __restrict__ A, const u16* __restrict__ B,
                                              u16* __restrict__ C, int M, int N, int K,
                                              const float* __restrict__ part, float* __restrict__ qm) {
  __shared__ u16 As[128 * 64], Bs[128 * 64];
  int tid = threadIdx.x;
  if (blockIdx.y == 16) {
    int bm = blockIdx.x;
    if (bm >= 8) return;
    int s = bm & 1, b = bm >> 1;
    int col = s * 1024 + tid * 4;
    f32x4 acc = {0.f, 0.f, 0.f, 0.f};
    #pragma unroll 8
    for (int y = 0; y < 32; ++y) {
      float4 v = *(const float4*)&part[((size_t)(b * 32 + y)) * Dq + col];
      acc[0] += v.x; acc[1] += v.y; acc[2] += v.z; acc[3] += v.w;
    }
    float4 st;
    st.x = acc[0] * (1.0f / Tq); st.y = acc[1] * (1.0f / Tq);
    st.z = acc[2] * (1.0f / Tq); st.w = acc[3] * (1.0f / Tq);
    *(float4*)&qm[(size_t)b * Dq + col] = st;
    return;
  }
  int lane = tid & 63, w = tid >> 6, wr = w >> 1, wc = w & 1;
  int bm = blockIdx.x, bn = blockIdx.y;
  const u16* Ab = A + (size_t)bm * 128 * K;
  const u16* Bb = B + (size_t)bn * 128 * K;
  f32x4 zero = {0.f, 0.f, 0.f, 0.f};
  f32x4 acc[4][4];
  #pragma unroll
  for (int mi = 0; mi < 4; ++mi)
    #pragma unroll
    for (int ni = 0; ni < 4; ++ni) acc[mi][ni] = zero;
  int ro = tid >> 3;
  int co = (tid & 7) * 8;
  int cs = co ^ ((ro & 7) * 8);
  for (int k0 = 0; k0 < K; k0 += 64) {
    #pragma unroll
    for (int i = 0; i < 4; ++i) {
      int row = ro + i * 32;
      async16(&As[row * 64 + co], Ab + (size_t)row * K + k0 + cs);
      async16(&Bs[row * 64 + co], Bb + (size_t)row * K + k0 + cs);
    }
    __syncthreads();
    #pragma unroll
    for (int ks = 0; ks < 2; ++ks) {
      int cbase = ks * 32 + ((lane >> 4) * 8);
      int crd = cbase ^ ((lane & 7) * 8);
      bf16x8 af[4], bfr[4];
      #pragma unroll
      for (int mi = 0; mi < 4; ++mi)
        af[mi] = *(const bf16x8*)&As[(wr * 64 + mi * 16 + (lane & 15)) * 64 + crd];
      #pragma unroll
      for (int ni = 0; ni < 4; ++ni)
        bfr[ni] = *(const bf16x8*)&Bs[(wc * 64 + ni * 16 + (lane & 15)) * 64 + crd];
      #pragma unroll
      for (int mi = 0; mi < 4; ++mi)
        #pragma unroll
        for (int ni = 0; ni < 4; ++ni)
          acc[mi][ni] = __builtin_amdgcn_mfma_f32_16x16x32_bf16(af[mi], bfr[ni], acc[mi][ni], 0, 0, 0);
    }
    __syncthreads();
  }
  int r0 = bm * 128 + wr * 64, c0 = bn * 128 + wc * 64;
  #pragma unroll
  for (int mi = 0; mi < 4; ++mi)
    #pragma unroll
    for (int ni = 0; ni < 4; ++ni) {
      int col = c0 + ni * 16 + (lane & 15);
      int rb = r0 + mi * 16 + ((lane >> 4) * 4);
      #pragma unroll
      for (int rg = 0; rg < 4; ++rg)
        C[(size_t)(rb + rg) * N + col] = f2bf(acc[mi][ni][rg]);
    }
}

// ---------------- banded salience (y<4) + in-block top-16 + embedded w0q (y==4) ----------------
// Each block covers rows [i0,i0+32) and ALL their window cols -> fused topk stage A.
__global__ __launch_bounds__(768) void k_band(const u16* __restrict__ Xn, const u16* __restrict__ XW0,
                                              const float* __restrict__ W0, const float* __restrict__ qm,
                                              float* __restrict__ w0q,
                                              float* __restrict__ cv, int* __restrict__ ci) {
  int tid = threadIdx.x, lane = tid & 63, w = tid >> 6;
  if (blockIdx.y == Bq) {
    int x = blockIdx.x;
    for (int r = w; r < 32; r += 12) {
      int d = x * 32 + r;
      const float* wr = W0 + (size_t)d * Dq;
      float a0 = 0, a1 = 0, a2 = 0, a3 = 0;
      for (int e = lane * 4; e < Dq; e += 256) {
        float4 wv = *(const float4*)&wr[e];
        float4 q0 = *(const float4*)&qm[0 * Dq + e];
        float4 q1 = *(const float4*)&qm[1 * Dq + e];
        float4 q2 = *(const float4*)&qm[2 * Dq + e];
        float4 q3 = *(const float4*)&qm[3 * Dq + e];
        a0 += wv.x*q0.x + wv.y*q0.y + wv.z*q0.z + wv.w*q0.w;
        a1 += wv.x*q1.x + wv.y*q1.y + wv.z*q1.z + wv.w*q1.w;
        a2 += wv.x*q2.x + wv.y*q2.y + wv.z*q2.z + wv.w*q2.w;
        a3 += wv.x*q3.x + wv.y*q3.y + wv.z*q3.z + wv.w*q3.w;
      }
      #pragma unroll
      for (int o = 32; o; o >>= 1) {
        a0 += __shfl_xor(a0, o); a1 += __shfl_xor(a1, o);
        a2 += __shfl_xor(a2, o); a3 += __shfl_xor(a3, o);
      }
      if (lane == 0) {
        w0q[0 * Dq + d] = a0; w0q[1 * Dq + d] = a1;
        w0q[2 * Dq + d] = a2; w0q[3 * Dq + d] = a3;
      }
    }
    return;
  }
  int b = blockIdx.y, i0 = blockIdx.x * 32;
  int mi = w / 6, ni = w % 6;
  const u16* Xb = Xn + (size_t)b * Tq * Dq;
  const u16* Wb = XW0 + (size_t)b * Tq * Dq;
  int koff = (lane >> 4) * 8;
  const u16* ap = Xb + (size_t)(i0 + mi * 16 + (lane & 15)) * Dq + koff;
  int j = i0 - 64 + ni * 16 + (lane & 15); j = min(max(j, 0), Tq - 1);
  const u16* bp = Wb + (size_t)j * Dq + koff;
  f32x4 zero = {0.f, 0.f, 0.f, 0.f};
  f32x4 accA = zero, accB = zero;
  for (int k = 0; k < Dq; k += 64) {
    bf16x8 a0 = *(const bf16x8*)(ap + k);
    bf16x8 b0 = *(const bf16x8*)(bp + k);
    bf16x8 a1 = *(const bf16x8*)(ap + k + 32);
    bf16x8 b1 = *(const bf16x8*)(bp + k + 32);
    accA = __builtin_amdgcn_mfma_f32_16x16x32_bf16(a0, b0, accA, 0, 0, 0);
    accB = __builtin_amdgcn_mfma_f32_16x16x32_bf16(a1, b1, accB, 0, 0, 0);
  }
  // ---- stage tile into LDS ----
  __shared__ float sal_s[32][64];
  __shared__ float Sv[512][4];
  __shared__ int Si[512][4];
  __shared__ int heads[512];
  for (int i = tid; i < 32 * 64; i += 768) ((float*)sal_s)[i] = NEG_INF;
  __syncthreads();
  int nl = ni * 16 + (lane & 15);
  #pragma unroll
  for (int rg = 0; rg < 4; ++rg) {
    int li = mi * 16 + (lane >> 4) * 4 + rg;
    int wb = nl - li;
    if (wb >= 0 && wb < 64) {
      int jj = i0 - 64 + nl;
      bool valid = (jj >= 0) && (i0 + li >= 1);
      sal_s[li][wb] = valid ? (accA[rg] + accB[rg]) : NEG_INF;
    }
  }
  __syncthreads();
  // ---- per-thread top-4 (512 scanners x 4 items = lossless) ----
  if (tid < 512) {
    float lv[4]; int li_[4];
    #pragma unroll
    for (int i = 0; i < 4; ++i) { lv[i] = NEG_INF; li_[i] = -1; }
    #pragma unroll
    for (int i = 0; i < 4; ++i) {
      int e = tid + i * 512;
      float v = ((float*)sal_s)[e];
      int idx = i0 * 64 + e;          // global flat = i*64 + wb
      if (v > lv[3]) {
        lv[3] = v; li_[3] = idx;
        #pragma unroll
        for (int q = 3; q > 0; --q)
          if (lv[q] > lv[q - 1]) {
            float tv = lv[q]; lv[q] = lv[q - 1]; lv[q - 1] = tv;
            int t2 = li_[q]; li_[q] = li_[q - 1]; li_[q - 1] = t2;
          }
      }
    }
    #pragma unroll
    for (int i = 0; i < 4; ++i) { Sv[tid][i] = lv[i]; Si[tid][i] = li_[i]; }
    heads[tid] = 0;
  }
  __syncthreads();
  // ---- merge 512 sorted 4-lists -> top-16 ----
  float* ov = cv + ((size_t)b * 64 + blockIdx.x) * 16;
  int* oi = ci + ((size_t)b * 64 + blockIdx.x) * 16;
  for (int r = 0; r < 16; ++r) {
    if (tid < 64) {
      float best = NEG_INF; int bl = 0; int bidx = 0x7fffffff;
      #pragma unroll
      for (int cc = 0; cc < 8; ++cc) {
        int c = tid + cc * 64;
        int h = heads[c];
        float v = (h < 4) ? Sv[c][h] : NEG_INF;
        int ix = (h < 4) ? Si[c][h] : 0x7fffffff;
        if (v > best || (v == best && ix < bidx)) { best = v; bl = c; bidx = ix; }
      }
      #pragma unroll
      for (int o = 32; o; o >>= 1) {
        float bv = __shfl_xor(best, o); int blx = __shfl_xor(bl, o); int bix = __shfl_xor(bidx, o);
        if (bv > best || (bv == best && bix < bidx)) { best = bv; bl = blx; bidx = bix; }
      }
      if (tid == 0) {
        int h = heads[bl];
        ov[r] = best; oi[r] = (h < 4) ? Si[bl][h] : -1;
        heads[bl] = h + 1;
      }
    }
    __syncthreads();
  }
}

// ---------------- top-16 stage B: merge 64 lists (x<Bq) + embedded basis (x>=Bq) ----------------
__global__ __launch_bounds__(256) void k_topk2(const float* __restrict__ cv, const int* __restrict__ ci,
                                               int* __restrict__ ti, int* __restrict__ tj,
                                               const float* __restrict__ qm, const float* __restrict__ w0q,
                                               float* __restrict__ basis) {
  int tid = threadIdx.x;
  if (blockIdx.x >= Bq) {
    int b = blockIdx.x - Bq;
    __shared__ float red[256];
    __shared__ float psum;
    float ps = 0, ss = 0;
    for (int d = tid; d < Dq; d += 256) {
      float qv = qm[b * Dq + d], wv = w0q[b * Dq + d];
      float ph = (wv - PSIc * qv) * (1.0f / DPHI);
      float pv = (PHIc * qv - wv) * (1.0f / DPHI);
      ps += ph * ph; ss += pv * pv;
    }
    red[tid] = ps; __syncthreads();
    for (int st = 128; st; st >>= 1) { if (tid < st) red[tid] += red[tid + st]; __syncthreads(); }
    if (tid == 0) psum = red[0];
    __syncthreads();
    red[tid] = ss; __syncthreads();
    for (int st = 128; st; st >>= 1) { if (tid < st) red[tid] += red[tid + st]; __syncthreads(); }
    if (tid == 0) {
      float pm = sqrtf(psum), sm = sqrtf(red[0]);
      float tot = pm + sm + 1e-6f;
      basis[b * 3 + 0] = 1.0f; basis[b * 3 + 1] = pm / tot; basis[b * 3 + 2] = sm / tot;
    }
    return;
  }
  int b = blockIdx.x;
  __shared__ float Sv[64][16];
  __shared__ int Si[64][16];
  __shared__ int heads[64];
  __shared__ int ridx[16];
  for (int i = tid; i < 64 * 16; i += 256) {
    ((float*)Sv)[i] = cv[(size_t)b * 1024 + i];
    ((int*)Si)[i] = ci[(size_t)b * 1024 + i];
  }
  if (tid < 64) heads[tid] = 0;
  __syncthreads();
  for (int r = 0; r < 16; ++r) {
    if (tid < 64) {
      int h = heads[tid];
      float best = (h < 16) ? Sv[tid][h] : NEG_INF;
      int bidx = (h < 16) ? Si[tid][h] : 0x7fffffff;
      int bl = tid;
      #pragma unroll
      for (int o = 32; o; o >>= 1) {
        float bv = __shfl_xor(best, o); int blx = __shfl_xor(bl, o); int bix = __shfl_xor(bidx, o);
        if (bv > best || (bv == best && bix < bidx)) { best = bv; bl = blx; bidx = bix; }
      }
      if (tid == 0) {
        int hh = heads[bl];
        ridx[r] = Si[bl][hh];
        heads[bl] = hh + 1;
      }
    }
    __syncthreads();
  }
  if (tid < 16) {
    int fi = ridx[tid];
    int ii = fi >> 6;
    int jj = ii + (fi & 63) - 64;
    ti[b * TK + tid] = ii;
    tj[b * TK + tid] = jj;
  }
}

// ---------------- gather + exact f32 LN (+psal zero) ----------------
__global__ __launch_bounds__(256) void k_gatherln(const float* __restrict__ X, const float* __restrict__ g,
    const float* __restrict__ bb, const int* __restrict__ ti, const int* __restrict__ tj,
    float* __restrict__ Xnew, float* __restrict__ Xold, float* __restrict__ psal) {
  int b = blockIdx.y, p = blockIdx.x >> 1, side = blockIdx.x & 1;
  int tid = threadIdx.x, lane = tid & 63, w = tid >> 6;
  if (blockIdx.x == 0 && tid < TK) psal[b * TK + tid] = 0.f;
  int row = side ? tj[b * TK + p] : ti[b * TK + p];
  row = min(max(row, 0), Tq - 1);
  const float* xr = X + ((size_t)(b * Tq + row)) * Dq;
  float* dst = (side ? Xold : Xnew) + ((size_t)(b * TK + p)) * Dq;
  float4 a = *(const float4*)&xr[tid * 8];
  float4 c = *(const float4*)&xr[tid * 8 + 4];
  float s = a.x + a.y + a.z + a.w + c.x + c.y + c.z + c.w;
  float q = a.x*a.x + a.y*a.y + a.z*a.z + a.w*a.w + c.x*c.x + c.y*c.y + c.z*c.z + c.w*c.w;
  #pragma unroll
  for (int o = 32; o; o >>= 1) { s += __shfl_xor(s, o); q += __shfl_xor(q, o); }
  __shared__ float red[8];
  if (lane == 0) { red[w] = s; red[w + 4] = q; }
  __syncthreads();
  float S = red[0] + red[1] + red[2] + red[3];
  float Q = red[4] + red[5] + red[6] + red[7];
  float mean = S * (1.0f / Dq);
  float var = Q * (1.0f / Dq) - mean * mean;
  float rstd = rsqrtf(var + 1e-5f);
  float v[8] = {a.x, a.y, a.z, a.w, c.x, c.y, c.z, c.w};
  float o8[8];
  #pragma unroll
  for (int j = 0; j < 8; ++j) {
    int d = tid * 8 + j;
    o8[j] = (v[j] - mean) * rstd * g[d] + bb[d];
  }
  float4 s0; s0.x = o8[0]; s0.y = o8[1]; s0.z = o8[2]; s0.w = o8[3];
  float4 s1; s1.x = o8[4]; s1.y = o8[5]; s1.z = o8[6]; s1.w = o8[7];
  *(float4*)&dst[tid * 8] = s0;
  *(float4*)&dst[tid * 8 + 4] = s1;
}

// ---------------- exact pair_sal v3 ----------------
__global__ __launch_bounds__(256) void k_pairsal(const float* __restrict__ W0, const float* __restrict__ Xnew,
                                                 const float* __restrict__ Xold, float* __restrict__ psal) {
  int d0 = blockIdx.x * 64, e0 = blockIdx.y * 64;
  int tid = threadIdx.x, P = tid & 63, dg = tid >> 6;
  f32x4 xo[16];
  #pragma unroll
  for (int i = 0; i < 16; ++i)
    xo[i] = *(const f32x4*)&Xold[(size_t)P * Dq + e0 + i * 4];
  int dbase = d0 + dg * 16;
  f32x4 xn[4];
  #pragma unroll
  for (int i = 0; i < 4; ++i)
    xn[i] = *(const f32x4*)&Xnew[(size_t)P * Dq + dbase + i * 4];
  float acc = 0.f;
  #pragma unroll
  for (int dd = 0; dd < 16; ++dd) {
    int d = __builtin_amdgcn_readfirstlane(dbase + dd);
    const float* wr = W0 + (size_t)d * Dq + e0;
    float i0 = 0.f, i1 = 0.f, i2 = 0.f, i3 = 0.f;
    #pragma unroll
    for (int i = 0; i < 16; ++i) {
      float4 wv = *(const float4*)&wr[i * 4];
      i0 += wv.x * xo[i][0]; i1 += wv.y * xo[i][1];
      i2 += wv.z * xo[i][2]; i3 += wv.w * xo[i][3];
    }
    acc += xn[dd >> 2][dd & 3] * ((i0 + i1) + (i2 + i3));
  }
  __shared__ float part[4][64];
  part[dg][P] = acc;
  __syncthreads();
  if (tid < 64)
    atomicAdd(&psal[tid], part[0][tid] + part[1][tid] + part[2][tid] + part[3][tid]);
}

// ---------------- alpha softmax + R_t ----------------
__global__ __launch_bounds__(256) void k_alphart(const float* __restrict__ psal, const float* __restrict__ Xnew,
    const float* __restrict__ Xold, const float* __restrict__ Wv, float* __restrict__ Rt) {
  int bx = blockIdx.x, b = blockIdx.y;
  int tid = threadIdx.x, lane = tid & 63, w = tid >> 6;
  __shared__ float al[16], xd[Dq];
  if (tid == 0) {
    float mx = NEG_INF;
    #pragma unroll
    for (int p = 0; p < 16; ++p) mx = fmaxf(mx, psal[b * 16 + p]);
    float ee[16]; float s = 0.f;
    #pragma unroll
    for (int p = 0; p < 16; ++p) { ee[p] = expf(psal[b * 16 + p] - mx); s += ee[p]; }
    #pragma unroll
    for (int p = 0; p < 16; ++p) al[p] = ee[p] / s;
  }
  __syncthreads();
  {
    int d0 = tid * 8;
    float a8[8] = {0, 0, 0, 0, 0, 0, 0, 0};
    #pragma unroll
    for (int p = 0; p < 16; ++p) {
      const float* xn = Xnew + (size_t)(b * 16 + p) * Dq + d0;
      const float* xo = Xold + (size_t)(b * 16 + p) * Dq + d0;
      float ap = al[p];
      float4 n0 = *(const float4*)xn;
      float4 n1 = *(const float4*)(xn + 4);
      float4 o0 = *(const float4*)xo;
      float4 o1 = *(const float4*)(xo + 4);
      a8[0] += ap * (n0.x - o0.x); a8[1] += ap * (n0.y - o0.y);
      a8[2] += ap * (n0.z - o0.z); a8[3] += ap * (n0.w - o0.w);
      a8[4] += ap * (n1.x - o1.x); a8[5] += ap * (n1.y - o1.y);
      a8[6] += ap * (n1.z - o1.z); a8[7] += ap * (n1.w - o1.w);
    }
    #pragma unroll
    for (int j = 0; j < 8; ++j) xd[d0 + j] = a8[j];
  }
  __syncthreads();
  int e = bx * 4 + w;
  const float* wr = Wv + (size_t)e * Dq;
  float s = 0.f;
  #pragma unroll 8
  for (int d = lane; d < Dq; d += 64) s += wr[d] * xd[d];
  #pragma unroll
  for (int o = 32; o; o >>= 1) s += __shfl_xor(s, o);
  if (lane == 0) Rt[b * DB + e] = s;
}

// ---------------- slots stage A: sk row + compat  (grid K x B) ----------------
__global__ __launch_bounds__(256) void ksl_a(const float* __restrict__ slots, const float* __restrict__ Wk,
    const float* __restrict__ skb, const float* __restrict__ Rt, const float* __restrict__ temps,
    float* __restrict__ compat) {
  int k = blockIdx.x, b = blockIdx.y;
  int tid = threadIdx.x, g = tid >> 4, sub = tid & 15;
  __shared__ float s_s[DB], r_s[DB], sk_s[DB];
  if (tid < DB) { s_s[tid] = slots[((size_t)(b * Kq + k)) * DB + tid]; r_s[tid] = Rt[b * DB + tid]; }
  __syncthreads();
  #pragma unroll
  for (int r = 0; r < 8; ++r) {
    int e = g * 8 + r;
    const float* wr = Wk + e * DB;
    float a = 0.f;
    #pragma unroll
    for (int j = 0; j < 8; ++j) a += wr[sub + j * 16] * s_s[sub + j * 16];
    a += __shfl_xor(a, 8); a += __shfl_xor(a, 4); a += __shfl_xor(a, 2); a += __shfl_xor(a, 1);
    if (sub == 0) sk_s[e] = a + skb[k * DB + e];
  }
  __syncthreads();
  if (tid < 64) {
    float a = sk_s[tid] * r_s[tid] + sk_s[tid + 64] * r_s[tid + 64];
    #pragma unroll
    for (int o = 32; o; o >>= 1) a += __shfl_xor(a, o);
    if (tid == 0) {
      float t = temps[k];
      compat[b * Kq + k] = a * SD * log1pf(expf(t));
    }
  }
}

// ---------------- slots stage C: inline softmax + gate + su + LN + qkv (grid K x B) ----------------
__global__ __launch_bounds__(256) void ksl_c(const float* __restrict__ slots, const float* __restrict__ Rt,
    const float* __restrict__ compat, const float* __restrict__ Wgw, const float* __restrict__ Wgb,
    const float* __restrict__ lng, const float* __restrict__ lnb,
    const float* __restrict__ Wsq, const float* __restrict__ Wsk, const float* __restrict__ Wsv,
    float* __restrict__ suOut, float* __restrict__ qqOut, float* __restrict__ kkOut,
    float* __restrict__ vvOut) {
  int k = blockIdx.x, b = blockIdx.y;
  int tid = threadIdx.x, g = tid >> 4, sub = tid & 15;
  __shared__ float s_s[DB], r_s[DB], su[DB], bnl[DB];
  __shared__ float mvm, mvr;
  if (tid < DB) { s_s[tid] = slots[((size_t)(b * Kq + k)) * DB + tid]; r_s[tid] = Rt[b * DB + tid]; }
  __syncthreads();
  float swk;
  {
    float cm[Kq]; float mx = NEG_INF;
    #pragma unroll
    for (int kk = 0; kk < Kq; ++kk) { cm[kk] = compat[b * Kq + kk]; mx = fmaxf(mx, cm[kk]); }
    float ssum = 0.f;
    #pragma unroll
    for (int kk = 0; kk < Kq; ++kk) { cm[kk] = expf(cm[kk] - mx); ssum += cm[kk]; }
    swk = cm[k] / ssum;
  }
  #pragma unroll
  for (int r = 0; r < 8; ++r) {
    int e = g * 8 + r;
    const float* wr = Wgw + e * 256;
    float a = 0.f;
    #pragma unroll
    for (int j = 0; j < 16; ++j) {
      int col = sub + j * 16;
      float x = (j < 8) ? s_s[col] : swk * r_s[col - 128];
      a += wr[col] * x;
    }
    a += __shfl_xor(a, 8); a += __shfl_xor(a, 4); a += __shfl_xor(a, 2); a += __shfl_xor(a, 1);
    if (sub == 0) {
      a += Wgb[e];
      float gv = 1.0f / (1.0f + expf(-a));
      float wrv = swk * r_s[e];
      su[e] = (1.0f - gv) * s_s[e] + gv * wrv;
    }
  }
  __syncthreads();
  if (tid < 64) {
    float v0 = su[tid], v1 = su[tid + 64];
    float s = v0 + v1, q = v0 * v0 + v1 * v1;
    #pragma unroll
    for (int o = 32; o; o >>= 1) { s += __shfl_xor(s, o); q += __shfl_xor(q, o); }
    if (tid == 0) {
      float m = s / DB; float va = q / DB - m * m;
      mvm = m; mvr = rsqrtf(va + 1e-5f);
    }
  }
  __syncthreads();
  if (tid < DB) {
    bnl[tid] = (su[tid] - mvm) * mvr * lng[tid] + lnb[tid];
    suOut[((size_t)(b * Kq + k)) * DB + tid] = su[tid];
  }
  __syncthreads();
  #pragma unroll
  for (int r = 0; r < 8; ++r) {
    int e = g * 8 + r;
    const float* wr1 = Wsq + e * DB;
    const float* wr2 = Wsk + e * DB;
    const float* wr3 = Wsv + e * DB;
    float a1 = 0.f, a2 = 0.f, a3 = 0.f;
    #pragma unroll
    for (int j = 0; j < 8; ++j) {
      float x = bnl[sub + j * 16];
      a1 += wr1[sub + j * 16] * x;
      a2 += wr2[sub + j * 16] * x;
      a3 += wr3[sub + j * 16] * x;
    }
    #pragma unroll
    for (int o = 8; o; o >>= 1) {
      a1 += __shfl_xor(a1, o); a2 += __shfl_xor(a2, o); a3 += __shfl_xor(a3, o);
    }
    if (sub == 0) {
      size_t oi = ((size_t)(b * Kq + k)) * DB + e;
      qqOut[oi] = a1; kkOut[oi] = a2; vvOut[oi] = a3;
    }
  }
}

// ---------------- slots stage D: att + ctx + sn + kr (grid K x B) ----------------
__global__ __launch_bounds__(256) void ksl_d(const float* __restrict__ suOut, const float* __restrict__ qqOut,
    const float* __restrict__ kkOut, const float* __restrict__ vvOut, const float* __restrict__ lam,
    const float* __restrict__ Wkr, float* __restrict__ snOut, float* __restrict__ krOut) {
  int k = blockIdx.x, b = blockIdx.y;
  int tid = threadIdx.x, g = tid >> 4, sub = tid & 15;
  __shared__ float qq[DB], kks[Kq][DB], vvs[Kq][DB], att[8], sn_s[DB];
  if (tid < DB) qq[tid] = qqOut[((size_t)(b * Kq + k)) * DB + tid];
  for (int i = tid; i < Kq * DB; i += 256) {
    ((float*)kks)[i] = kkOut[(size_t)b * Kq * DB + i];
    ((float*)vvs)[i] = vvOut[(size_t)b * Kq * DB + i];
  }
  __syncthreads();
  if (tid < 112) {
    int m = g;
    float a = 0.f;
    #pragma unroll
    for (int j = 0; j < 8; ++j) a += qq[sub + j * 16] * kks[m][sub + j * 16];
    a += __shfl_xor(a, 8); a += __shfl_xor(a, 4); a += __shfl_xor(a, 2); a += __shfl_xor(a, 1);
    if (sub == 0) att[m] = a * SD;
  }
  __syncthreads();
  if (tid == 0) {
    float mx = att[0];
    for (int m = 1; m < Kq; ++m) mx = fmaxf(mx, att[m]);
    float s = 0.f;
    for (int m = 0; m < Kq; ++m) { att[m] = expf(att[m] - mx); s += att[m]; }
    for (int m = 0; m < Kq; ++m) att[m] /= s;
  }
  __syncthreads();
  if (tid < DB) {
    float c = 0.f;
    #pragma unroll
    for (int m = 0; m < Kq; ++m) c += att[m] * vvs[m][tid];
    float l = tanhf(lam[tid]); l = fminf(fmaxf(l, -1.0f), 1.0f);
    float v = suOut[((size_t)(b * Kq + k)) * DB + tid] + c * l;
    sn_s[tid] = v;
    snOut[((size_t)(b * Kq + k)) * DB + tid] = v;
  }
  __syncthreads();
  #pragma unroll
  for (int r = 0; r < 8; ++r) {
    int e = g * 8 + r;
    const float* wr = Wkr + e * DB;
    float a = 0.f;
    #pragma unroll
    for (int j = 0; j < 8; ++j) a += wr[sub + j * 16] * sn_s[sub + j * 16];
    a += __shfl_xor(a, 8); a += __shfl_xor(a, 4); a += __shfl_xor(a, 2); a += __shfl_xor(a, 1);
    if (sub == 0) krOut[((size_t)(b * Kq + k)) * DB + e] = a;
  }
}

// ---------------- M/Vg (bx<8) + aux losses (bx==8, b==0) ----------------
__global__ __launch_bounds__(256) void k_mvg(const float* __restrict__ snOut, const float* __restrict__ krOut,
    const float* __restrict__ Wqr, const float* __restrict__ Wvr, const float* __restrict__ rc,
    const float* __restrict__ basis, const float* __restrict__ slots,
    u16* __restrict__ Mb, u16* __restrict__ Vgb, float* __restrict__ out2) {
  int b = blockIdx.y, tid = threadIdx.x;
  if (blockIdx.x == 8) {
    if (b != 0) return;
    __shared__ float red[256];
    __shared__ float nrm[28];
    float p = 0.f;
    for (int i = tid; i < Bq * Kq * DB; i += 256) { float d = snOut[i] - slots[i]; p += d * d; }
    red[tid] = p; __syncthreads();
    for (int st = 128; st; st >>= 1) { if (tid < st) red[tid] += red[tid + st]; __syncthreads(); }
    if (tid == 0) out2[0] = red[0] / (float)(Bq * Kq * DB);
    if (tid < 28) {
      int bb2 = tid / 7, k = tid % 7;
      float s = 0.f;
      for (int e = 0; e < DB; ++e) { float v = snOut[(size_t)(bb2 * 7 + k) * DB + e]; s += v * v; }
      nrm[tid] = fmaxf(sqrtf(s), 1e-12f);
    }
    __syncthreads();
    float dv = 0.f;
    if (tid < 168) {
      int bb2 = tid / 42, r = tid % 42;
      int k = r / 6, m = r % 6; m += (m >= k);
      float dot = 0.f;
      for (int e = 0; e < DB; ++e)
        dot += snOut[(size_t)(bb2 * 7 + k) * DB + e] * snOut[(size_t)(bb2 * 7 + m) * DB + e];
      float c = dot / (nrm[bb2 * 7 + k] * nrm[bb2 * 7 + m]);
      dv = c * c;
    }
    red[tid] = dv; __syncthreads();
    for (int st = 128; st; st >>= 1) { if (tid < st) red[tid] += red[tid + st]; __syncthreads(); }
    if (tid == 0) out2[1] = red[0] / 168.0f;
    return;
  }
  int d = blockIdx.x * 256 + tid;
  __shared__ float krs[Kq][DB], sns[Kq][DB];
  for (int i = tid; i < Kq * DB; i += 256) {
    ((float*)krs)[i] = krOut[(size_t)b * Kq * DB + i];
    ((float*)sns)[i] = snOut[(size_t)b * Kq * DB + i];
  }
  __syncthreads();
  float b0 = basis[b * 3 + 0], b1 = basis[b * 3 + 1], b2 = basis[b * 3 + 2];
  float am[7] = {0, 0, 0, 0, 0, 0, 0};
  for (int e = 0; e < DB; ++e) {
    float wq = Wqr[(size_t)e * Dq + d];
    #pragma unroll
    for (int k = 0; k < 7; ++k) am[k] += krs[k][e] * wq;
  }
  float vr[7] = {0, 0, 0, 0, 0, 0, 0};
  const float* wvrow = Wvr + (size_t)d * DB;
  for (int e = 0; e < DB; ++e) {
    float wv = wvrow[e];
    #pragma unroll
    for (int k = 0; k < 7; ++k) vr[k] += sns[k][e] * wv;
  }
  #pragma unroll
  for (int k = 0; k < 7; ++k) {
    Mb[((size_t)b * 7 + k) * Dq + d] = f2bf(am[k]);
    float gt = tanhf(b0 * rc[((size_t)k * 3 + 0) * Dq + d] +
                     b1 * rc[((size_t)k * 3 + 1) * Dq + d] +
                     b2 * rc[((size_t)k * 3 + 2) * Dq + d]);
    gt = fminf(fmaxf(gt, -1.0f), 1.0f);
    Vgb[((size_t)b * 7 + k) * Dq + d] = f2bf(vr[k] * gt);
  }
}

// ---------------- final render read: direct L2 reads ----------------
__global__ __launch_bounds__(256) void k_z(const float* __restrict__ X, const u16* __restrict__ Mb,
                                           const u16* __restrict__ Vgb, float* __restrict__ Z) {
  int b = blockIdx.y, t0 = blockIdx.x * 16;
  int tid = threadIdx.x, lane = tid & 63, w = tid >> 6;
  const u16* Ms = Mb + (size_t)b * 7 * 2048;
  const u16* Vs = Vgb + (size_t)b * 7 * 2048;
  for (int ri = 0; ri < 4; ++ri) {
    int t = t0 + ri * 4 + w;
    const float* xr = X + ((size_t)b * Tq + t) * Dq;
    float sc[7] = {0, 0, 0, 0, 0, 0, 0};
    #pragma unroll
    for (int i = 0; i < 8; ++i) {
      int d = lane * 4 + i * 256;
      float4 x = *(const float4*)&xr[d];
      #pragma unroll
      for (int k = 0; k < 7; ++k) {
        uint2 mm = *(const uint2*)&Ms[k * 2048 + d];
        sc[k] += x.x * bfbits2f(mm.x & 0xffffu) + x.y * bfbits2f(mm.x >> 16)
               + x.z * bfbits2f(mm.y & 0xffffu) + x.w * bfbits2f(mm.y >> 16);
      }
    }
    #pragma unroll
    for (int k = 0; k < 7; ++k) {
      #pragma unroll
      for (int o = 32; o; o >>= 1) sc[k] += __shfl_xor(sc[k], o);
    }
    float mx = sc[0];
    #pragma unroll
    for (int k = 1; k < 7; ++k) mx = fmaxf(mx, sc[k]);
    float pz[7]; float s = 0.f;
    #pragma unroll
    for (int k = 0; k < 7; ++k) { pz[k] = expf((sc[k] - mx) * SD); s += pz[k]; }
    float inv = 1.0f / s;
    #pragma unroll
    for (int k = 0; k < 7; ++k) pz[k] *= inv;
    float* zr = Z + ((size_t)b * Tq + t) * Dq;
    #pragma unroll
    for (int i = 0; i < 8; ++i) {
      int d = lane * 4 + i * 256;
      float4 o4; o4.x = o4.y = o4.z = o4.w = 0.f;
      #pragma unroll
      for (int k = 0; k < 7; ++k) {
        uint2 vm = *(const uint2*)&Vs[k * 2048 + d];
        float pk = pz[k];
        o4.x += pk * bfbits2f(vm.x & 0xffffu); o4.y += pk * bfbits2f(vm.x >> 16);
        o4.z += pk * bfbits2f(vm.y & 0xffffu); o4.w += pk * bfbits2f(vm.y >> 16);
      }
      *(float4*)&zr[d] = o4;
    }
  }
}

extern "C" void kernel_launch(void* const* d_in, const int* in_sizes, int n_in,
                              void* d_out, int out_size, void* d_ws, size_t ws_size,
                              hipStream_t stream) {
  const float* Xw   = (const float*)d_in[0];
  const float* Xr   = (const float*)d_in[1];
  const float* slots= (const float*)d_in[2];
  const float* W0   = (const float*)d_in[3];
  const float* lng  = (const float*)d_in[4];
  const float* lnb  = (const float*)d_in[5];
  const float* Wv   = (const float*)d_in[6];
  const float* Wk   = (const float*)d_in[7];
  const float* skb  = (const float*)d_in[8];
  const float* Wgw  = (const float*)d_in[9];
  const float* Wgb  = (const float*)d_in[10];
  const float* lsg  = (const float*)d_in[11];
  const float* lsb  = (const float*)d_in[12];
  const float* Wsq  = (const float*)d_in[13];
  const float* Wsk  = (const float*)d_in[14];
  const float* Wsv  = (const float*)d_in[15];
  const float* lam  = (const float*)d_in[16];
  const float* Wqr  = (const float*)d_in[17];
  const float* Wkr  = (const float*)d_in[18];
  const float* Wvr  = (const float*)d_in[19];
  const float* rc   = (const float*)d_in[20];
  const float* temps= (const float*)d_in[21];

  char* wsb = (char*)d_ws;
  size_t off = 0;
  auto alloc = [&](size_t bytes) -> void* {
    void* p = wsb + off;
    off += (bytes + 255) & ~(size_t)255;
    return p;
  };
  u16*   Xn   = (u16*)  alloc((size_t)Bq * Tq * Dq * 2);
  u16*   XW0  = (u16*)  alloc((size_t)Bq * Tq * Dq * 2);
  u16*   W0b  = (u16*)  alloc((size_t)Dq * Dq * 2);
  int*   ti   = (int*)  alloc(Bq * TK * 4);
  int*   tj   = (int*)  alloc(Bq * TK * 4);
  float* Xnew = (float*)alloc((size_t)Bq * TK * Dq * 4);
  float* Xold = (float*)alloc((size_t)Bq * TK * Dq * 4);
  float* psal = (float*)alloc(Bq * TK * 4);
  float* Rt   = (float*)alloc(Bq * DB * 4);
  float* qm   = (float*)alloc(Bq * Dq * 4);
  float* w0q  = (float*)alloc(Bq * Dq * 4);
  float* basis= (float*)alloc(Bq * 3 * 4);
  float* krOut= (float*)alloc(Bq * Kq * DB * 4);
  u16*   Mbf  = (u16*)  alloc((size_t)Bq * Kq * Dq * 2);
  u16*   Vgb  = (u16*)  alloc((size_t)Bq * Kq * Dq * 2);
  float* cv   = (float*)alloc((size_t)Bq * 64 * 16 * 4);
  int*   ci   = (int*)  alloc((size_t)Bq * 64 * 16 * 4);
  float* part = (float*)alloc((size_t)Bq * 32 * Dq * 4);
  float* compat = (float*)alloc(Bq * Kq * 4);
  float* suB  = (float*)alloc(Bq * Kq * DB * 4);
  float* qqB  = (float*)alloc(Bq * Kq * DB * 4);
  float* kkB  = (float*)alloc(Bq * Kq * DB * 4);
  float* vvB  = (float*)alloc(Bq * Kq * DB * 4);

  float* Zout = (float*)d_out;
  float* snOut = Zout + (size_t)Bq * Tq * Dq;
  float* lossOut = snOut + Bq * Kq * DB;

  k_prep  <<<2048 + 8192 + 256, 256, 0, stream>>>(W0, W0b, Xw, lng, lnb, Xn, Xr, part);
  k_gemm  <<<dim3(64, 17), 256, 0, stream>>>(Xn, W0b, XW0, Bq * Tq, Dq, Dq, part, qm);
  k_band  <<<dim3(64, Bq + 1), 768, 0, stream>>>(Xn, XW0, W0, qm, w0q, cv, ci);
  k_topk2 <<<2 * Bq, 256, 0, stream>>>(cv, ci, ti, tj, qm, w0q, basis);
  k_gatherln<<<dim3(32, Bq), 256, 0, stream>>>(Xw, lng, lnb, ti, tj, Xnew, Xold, psal);
  k_pairsal<<<dim3(32, 32), 256, 0, stream>>>(W0, Xnew, Xold, psal);
  k_alphart<<<dim3(32, Bq), 256, 0, stream>>>(psal, Xnew, Xold, Wv, Rt);
  ksl_a   <<<dim3(Kq, Bq), 256, 0, stream>>>(slots, Wk, skb, Rt, temps, compat);
  ksl_c   <<<dim3(Kq, Bq), 256, 0, stream>>>(slots, Rt, compat, Wgw, Wgb, lsg, lsb,
                                             Wsq, Wsk, Wsv, suB, qqB, kkB, vvB);
  ksl_d   <<<dim3(Kq, Bq), 256, 0, stream>>>(suB, qqB, kkB, vvB, lam, Wkr, snOut, krOut);
  k_mvg   <<<dim3(9, Bq), 256, 0, stream>>>(snOut, krOut, Wqr, Wvr, rc, basis, slots,
                                            Mbf, Vgb, lossOut);
  k_z     <<<dim3(128, Bq), 256, 0, stream>>>(Xr, Mbf, Vgb, Zout);
}

// Round 14
// 399.895 us; speedup vs baseline: 1.1967x; 1.1967x over previous
//
#include <hip/hip_runtime.h>
#include <cstdint>
#include <cstddef>

#define DEV __device__ __forceinline__

typedef __bf16 bf16x8 __attribute__((ext_vector_type(8)));
typedef float f32x4 __attribute__((ext_vector_type(4)));
typedef unsigned short u16;
typedef unsigned int u32;

constexpr int Bq = 4, Tq = 2048, Dq = 2048, Kq = 7, DB = 128, TK = 16;
constexpr float SD = 0.08838834764831845f;          // 1/sqrt(128)
constexpr float PHIc = 1.618033988749895f;
constexpr float PSIc = -0.6180339887498949f;
constexpr float DPHI = 2.2360679774997896f;          // PHI - PSI = sqrt(5)
#define NEG_INF (-__builtin_inff())

DEV u16 f2bf(float f) {
  union { float f; u32 u; } x; x.f = f;
  u32 r = (x.u + 0x7fffu + ((x.u >> 16) & 1u)) >> 16;
  return (u16)r;
}
DEV float bfbits2f(u32 h) { union { u32 u; float f; } x; x.u = h << 16; return x.f; }

DEV void async16(void* l, const void* g) {
  __builtin_amdgcn_global_load_lds((const __attribute__((address_space(1))) void*)g,
                                   (__attribute__((address_space(3))) void*)l, 16, 0, 0);
}

// ---------------- fused prep: W0->bf16  |  LN rows -> bf16  |  qmean stage 1 ----------------
__global__ __launch_bounds__(256) void k_prep(const float* __restrict__ W0, u16* __restrict__ W0b,
                                              const float* __restrict__ Xw, const float* __restrict__ g,
                                              const float* __restrict__ bb, u16* __restrict__ Xn,
                                              const float* __restrict__ Xr, float* __restrict__ part) {
  int bid = blockIdx.x;
  int tid = threadIdx.x;
  if (bid < 2048) {
    size_t i = ((size_t)bid * 256 + tid) * 8;
    float4 a = *(const float4*)&W0[i];
    float4 c = *(const float4*)&W0[i + 4];
    u32 p0 = (u32)f2bf(a.x) | ((u32)f2bf(a.y) << 16);
    u32 p1 = (u32)f2bf(a.z) | ((u32)f2bf(a.w) << 16);
    u32 p2 = (u32)f2bf(c.x) | ((u32)f2bf(c.y) << 16);
    u32 p3 = (u32)f2bf(c.z) | ((u32)f2bf(c.w) << 16);
    uint4 st; st.x = p0; st.y = p1; st.z = p2; st.w = p3;
    *(uint4*)&W0b[i] = st;
  } else if (bid < 2048 + 8192) {
    int row = bid - 2048;
    const float* xr = Xw + (size_t)row * Dq;
    int lane = tid & 63, w = tid >> 6;
    float4 a = *(const float4*)&xr[tid * 8];
    float4 c = *(const float4*)&xr[tid * 8 + 4];
    float s = a.x + a.y + a.z + a.w + c.x + c.y + c.z + c.w;
    float q = a.x*a.x + a.y*a.y + a.z*a.z + a.w*a.w + c.x*c.x + c.y*c.y + c.z*c.z + c.w*c.w;
    #pragma unroll
    for (int o = 32; o; o >>= 1) { s += __shfl_xor(s, o); q += __shfl_xor(q, o); }
    __shared__ float red[8];
    if (lane == 0) { red[w] = s; red[w + 4] = q; }
    __syncthreads();
    float S = red[0] + red[1] + red[2] + red[3];
    float Q = red[4] + red[5] + red[6] + red[7];
    float mean = S * (1.0f / Dq);
    float var = Q * (1.0f / Dq) - mean * mean;
    float rstd = rsqrtf(var + 1e-5f);
    float v[8] = {a.x, a.y, a.z, a.w, c.x, c.y, c.z, c.w};
    u32 p[4];
    #pragma unroll
    for (int j = 0; j < 4; ++j) {
      int d0 = tid * 8 + j * 2;
      float o0 = (v[j*2]   - mean) * rstd * g[d0]   + bb[d0];
      float o1 = (v[j*2+1] - mean) * rstd * g[d0+1] + bb[d0+1];
      p[j] = (u32)f2bf(o0) | ((u32)f2bf(o1) << 16);
    }
    uint4 st; st.x = p[0]; st.y = p[1]; st.z = p[2]; st.w = p[3];
    *(uint4*)&Xn[(size_t)row * Dq + tid * 8] = st;
  } else {
    int f = bid - (2048 + 8192);
    int s = f & 1, y = (f >> 1) & 31, b = f >> 6;
    const float* xb = Xr + (size_t)b * Tq * Dq + (size_t)s * 1024 + tid * 4;
    f32x4 acc = {0.f, 0.f, 0.f, 0.f};
    #pragma unroll 4
    for (int t = 0; t < 64; ++t) {
      const float4 v = *(const float4*)&xb[(size_t)(y * 64 + t) * Dq];
      acc[0] += v.x; acc[1] += v.y; acc[2] += v.z; acc[3] += v.w;
    }
    float4 st; st.x = acc[0]; st.y = acc[1]; st.z = acc[2]; st.w = acc[3];
    *(float4*)&part[((size_t)(b * 32 + y)) * Dq + s * 1024 + tid * 4] = st;
  }
}

// ---------------- big GEMM (T2 swizzle) + embedded qmean2 (y==16) ----------------
__global__ __launch_bounds__(256) void k_gemm(const u16* __restrict__ A, const u16* __restrict__ B,
                                              u16* __restrict__ C, int M, int N, int K,
                                              const float* __restrict__ part, float* __restrict__ qm) {
  __shared__ u16 As[128 * 64], Bs[128 * 64];
  int tid = threadIdx.x;
  if (blockIdx.y == 16) {
    int bm = blockIdx.x;
    if (bm >= 8) return;
    int s = bm & 1, b = bm >> 1;
    int col = s * 1024 + tid * 4;
    f32x4 acc = {0.f, 0.f, 0.f, 0.f};
    #pragma unroll 8
    for (int y = 0; y < 32; ++y) {
      float4 v = *(const float4*)&part[((size_t)(b * 32 + y)) * Dq + col];
      acc[0] += v.x; acc[1] += v.y; acc[2] += v.z; acc[3] += v.w;
    }
    float4 st;
    st.x = acc[0] * (1.0f / Tq); st.y = acc[1] * (1.0f / Tq);
    st.z = acc[2] * (1.0f / Tq); st.w = acc[3] * (1.0f / Tq);
    *(float4*)&qm[(size_t)b * Dq + col] = st;
    return;
  }
  int lane = tid & 63, w = tid >> 6, wr = w >> 1, wc = w & 1;
  int bm = blockIdx.x, bn = blockIdx.y;
  const u16* Ab = A + (size_t)bm * 128 * K;
  const u16* Bb = B + (size_t)bn * 128 * K;
  f32x4 zero = {0.f, 0.f, 0.f, 0.f};
  f32x4 acc[4][4];
  #pragma unroll
  for (int mi = 0; mi < 4; ++mi)
    #pragma unroll
    for (int ni = 0; ni < 4; ++ni) acc[mi][ni] = zero;
  int ro = tid >> 3;
  int co = (tid & 7) * 8;
  int cs = co ^ ((ro & 7) * 8);
  for (int k0 = 0; k0 < K; k0 += 64) {
    #pragma unroll
    for (int i = 0; i < 4; ++i) {
      int row = ro + i * 32;
      async16(&As[row * 64 + co], Ab + (size_t)row * K + k0 + cs);
      async16(&Bs[row * 64 + co], Bb + (size_t)row * K + k0 + cs);
    }
    __syncthreads();
    #pragma unroll
    for (int ks = 0; ks < 2; ++ks) {
      int cbase = ks * 32 + ((lane >> 4) * 8);
      int crd = cbase ^ ((lane & 7) * 8);
      bf16x8 af[4], bfr[4];
      #pragma unroll
      for (int mi = 0; mi < 4; ++mi)
        af[mi] = *(const bf16x8*)&As[(wr * 64 + mi * 16 + (lane & 15)) * 64 + crd];
      #pragma unroll
      for (int ni = 0; ni < 4; ++ni)
        bfr[ni] = *(const bf16x8*)&Bs[(wc * 64 + ni * 16 + (lane & 15)) * 64 + crd];
      #pragma unroll
      for (int mi = 0; mi < 4; ++mi)
        #pragma unroll
        for (int ni = 0; ni < 4; ++ni)
          acc[mi][ni] = __builtin_amdgcn_mfma_f32_16x16x32_bf16(af[mi], bfr[ni], acc[mi][ni], 0, 0, 0);
    }
    __syncthreads();
  }
  int r0 = bm * 128 + wr * 64, c0 = bn * 128 + wc * 64;
  #pragma unroll
  for (int mi = 0; mi < 4; ++mi)
    #pragma unroll
    for (int ni = 0; ni < 4; ++ni) {
      int col = c0 + ni * 16 + (lane & 15);
      int rb = r0 + mi * 16 + ((lane >> 4) * 4);
      #pragma unroll
      for (int rg = 0; rg < 4; ++rg)
        C[(size_t)(rb + rg) * N + col] = f2bf(acc[mi][ni][rg]);
    }
}

// ---------------- banded salience (y<4) + embedded w0q (y==4) ----------------
__global__ __launch_bounds__(768) void k_band(const u16* __restrict__ Xn, const u16* __restrict__ XW0,
                                              float* __restrict__ sal,
                                              const float* __restrict__ W0, const float* __restrict__ qm,
                                              float* __restrict__ w0q) {
  int tid = threadIdx.x, lane = tid & 63, w = tid >> 6;
  if (blockIdx.y == Bq) {
    int x = blockIdx.x;
    for (int r = w; r < 32; r += 12) {
      int d = x * 32 + r;
      const float* wr = W0 + (size_t)d * Dq;
      float a0 = 0, a1 = 0, a2 = 0, a3 = 0;
      for (int e = lane * 4; e < Dq; e += 256) {
        float4 wv = *(const float4*)&wr[e];
        float4 q0 = *(const float4*)&qm[0 * Dq + e];
        float4 q1 = *(const float4*)&qm[1 * Dq + e];
        float4 q2 = *(const float4*)&qm[2 * Dq + e];
        float4 q3 = *(const float4*)&qm[3 * Dq + e];
        a0 += wv.x*q0.x + wv.y*q0.y + wv.z*q0.z + wv.w*q0.w;
        a1 += wv.x*q1.x + wv.y*q1.y + wv.z*q1.z + wv.w*q1.w;
        a2 += wv.x*q2.x + wv.y*q2.y + wv.z*q2.z + wv.w*q2.w;
        a3 += wv.x*q3.x + wv.y*q3.y + wv.z*q3.z + wv.w*q3.w;
      }
      #pragma unroll
      for (int o = 32; o; o >>= 1) {
        a0 += __shfl_xor(a0, o); a1 += __shfl_xor(a1, o);
        a2 += __shfl_xor(a2, o); a3 += __shfl_xor(a3, o);
      }
      if (lane == 0) {
        w0q[0 * Dq + d] = a0; w0q[1 * Dq + d] = a1;
        w0q[2 * Dq + d] = a2; w0q[3 * Dq + d] = a3;
      }
    }
    return;
  }
  int b = blockIdx.y, i0 = blockIdx.x * 32;
  int mi = w / 6, ni = w % 6;
  const u16* Xb = Xn + (size_t)b * Tq * Dq;
  const u16* Wb = XW0 + (size_t)b * Tq * Dq;
  int koff = (lane >> 4) * 8;
  const u16* ap = Xb + (size_t)(i0 + mi * 16 + (lane & 15)) * Dq + koff;
  int j = i0 - 64 + ni * 16 + (lane & 15); j = min(max(j, 0), Tq - 1);
  const u16* bp = Wb + (size_t)j * Dq + koff;
  f32x4 zero = {0.f, 0.f, 0.f, 0.f};
  f32x4 accA = zero, accB = zero;
  for (int k = 0; k < Dq; k += 64) {
    bf16x8 a0 = *(const bf16x8*)(ap + k);
    bf16x8 b0 = *(const bf16x8*)(bp + k);
    bf16x8 a1 = *(const bf16x8*)(ap + k + 32);
    bf16x8 b1 = *(const bf16x8*)(bp + k + 32);
    accA = __builtin_amdgcn_mfma_f32_16x16x32_bf16(a0, b0, accA, 0, 0, 0);
    accB = __builtin_amdgcn_mfma_f32_16x16x32_bf16(a1, b1, accB, 0, 0, 0);
  }
  int nl = ni * 16 + (lane & 15);
  #pragma unroll
  for (int rg = 0; rg < 4; ++rg) {
    int i = i0 + mi * 16 + (lane >> 4) * 4 + rg;
    int wb = nl - (i - i0);
    if (wb >= 0 && wb < 64) {
      int jj = i0 - 64 + nl;
      bool valid = (jj >= 0) && (i >= 1);
      sal[((size_t)b * Tq + i) * 64 + wb] = valid ? (accA[rg] + accB[rg]) : NEG_INF;
    }
  }
}

// ---------------- top-16 stage A (x<128) + embedded basis (x==128) ----------------
__global__ __launch_bounds__(256) void k_topk1(const float* __restrict__ sal,
                                               float* __restrict__ cv, int* __restrict__ ci,
                                               const float* __restrict__ qm, const float* __restrict__ w0q,
                                               float* __restrict__ basis) {
  int b = blockIdx.y, tid = threadIdx.x, lane = tid & 63;
  if (blockIdx.x == 128) {
    __shared__ float red[256];
    __shared__ float psum;
    float ps = 0, ss = 0;
    for (int d = tid; d < Dq; d += 256) {
      float qv = qm[b * Dq + d], wv = w0q[b * Dq + d];
      float ph = (wv - PSIc * qv) * (1.0f / DPHI);
      float pv = (PHIc * qv - wv) * (1.0f / DPHI);
      ps += ph * ph; ss += pv * pv;
    }
    red[tid] = ps; __syncthreads();
    for (int st = 128; st; st >>= 1) { if (tid < st) red[tid] += red[tid + st]; __syncthreads(); }
    if (tid == 0) psum = red[0];
    __syncthreads();
    red[tid] = ss; __syncthreads();
    for (int st = 128; st; st >>= 1) { if (tid < st) red[tid] += red[tid + st]; __syncthreads(); }
    if (tid == 0) {
      float pm = sqrtf(psum), sm = sqrtf(red[0]);
      float tot = pm + sm + 1e-6f;
      basis[b * 3 + 0] = 1.0f; basis[b * 3 + 1] = pm / tot; basis[b * 3 + 2] = sm / tot;
    }
    return;
  }
  int chunk = blockIdx.x;
  const float* s = sal + (size_t)b * Tq * 64 + (size_t)chunk * 1024;
  float lv[4]; int li[4];
  #pragma unroll
  for (int i = 0; i < 4; ++i) { lv[i] = NEG_INF; li[i] = -1; }
  #pragma unroll
  for (int i = 0; i < 4; ++i) {
    int e = tid + i * 256;
    float v = s[e];
    int idx = chunk * 1024 + e;
    if (v > lv[3]) {
      lv[3] = v; li[3] = idx;
      #pragma unroll
      for (int q = 3; q > 0; --q)
        if (lv[q] > lv[q - 1]) {
          float tv = lv[q]; lv[q] = lv[q - 1]; lv[q - 1] = tv;
          int t2 = li[q]; li[q] = li[q - 1]; li[q - 1] = t2;
        }
    }
  }
  __shared__ float Sv[256][4];
  __shared__ int Si[256][4];
  __shared__ int heads[256];
  #pragma unroll
  for (int i = 0; i < 4; ++i) { Sv[tid][i] = lv[i]; Si[tid][i] = li[i]; }
  heads[tid] = 0;
  __syncthreads();
  float* ov = cv + ((size_t)b * 128 + chunk) * 16;
  int* oi = ci + ((size_t)b * 128 + chunk) * 16;
  for (int r = 0; r < 16; ++r) {
    if (tid < 64) {
      float best = NEG_INF; int bl = 0; int bidx = 0x7fffffff;
      #pragma unroll
      for (int cc = 0; cc < 4; ++cc) {
        int c = lane + cc * 64;
        int h = heads[c];
        float v = (h < 4) ? Sv[c][h] : NEG_INF;
        int ix = (h < 4) ? Si[c][h] : 0x7fffffff;
        if (v > best || (v == best && ix < bidx)) { best = v; bl = c; bidx = ix; }
      }
      #pragma unroll
      for (int o = 32; o; o >>= 1) {
        float bv = __shfl_xor(best, o); int blx = __shfl_xor(bl, o); int bix = __shfl_xor(bidx, o);
        if (bv > best || (bv == best && bix < bidx)) { best = bv; bl = blx; bidx = bix; }
      }
      if (lane == 0) {
        int h = heads[bl];
        ov[r] = best; oi[r] = (h < 4) ? Si[bl][h] : -1;
        heads[bl] = h + 1;
      }
    }
    __syncthreads();
  }
}

// ---------------- top-16: stage B ----------------
__global__ __launch_bounds__(256) void k_topk2(const float* __restrict__ cv, const int* __restrict__ ci,
                                               int* __restrict__ ti, int* __restrict__ tj) {
  int b = blockIdx.x, tid = threadIdx.x, lane = tid & 63;
  __shared__ float Sv[128][16];
  __shared__ int Si[128][16];
  __shared__ int heads[128];
  __shared__ int ridx[16];
  for (int i = tid; i < 128 * 16; i += 256) {
    ((float*)Sv)[i] = cv[(size_t)b * 2048 + i];
    ((int*)Si)[i] = ci[(size_t)b * 2048 + i];
  }
  if (tid < 128) heads[tid] = 0;
  __syncthreads();
  for (int r = 0; r < 16; ++r) {
    if (tid < 64) {
      float best = NEG_INF; int bl = 0; int bidx = 0x7fffffff;
      #pragma unroll
      for (int cc = 0; cc < 2; ++cc) {
        int c = lane + cc * 64;
        int h = heads[c];
        float v = (h < 16) ? Sv[c][h] : NEG_INF;
        int ix = (h < 16) ? Si[c][h] : 0x7fffffff;
        if (v > best || (v == best && ix < bidx)) { best = v; bl = c; bidx = ix; }
      }
      #pragma unroll
      for (int o = 32; o; o >>= 1) {
        float bv = __shfl_xor(best, o); int blx = __shfl_xor(bl, o); int bix = __shfl_xor(bidx, o);
        if (bv > best || (bv == best && bix < bidx)) { best = bv; bl = blx; bidx = bix; }
      }
      if (lane == 0) {
        int h = heads[bl];
        ridx[r] = Si[bl][h];
        heads[bl] = h + 1;
      }
    }
    __syncthreads();
  }
  if (tid < 16) {
    int fi = ridx[tid];
    int ii = fi >> 6;
    int jj = ii + (fi & 63) - 64;
    ti[b * TK + tid] = ii;
    tj[b * TK + tid] = jj;
  }
}

// ---------------- gather + exact f32 LN (+psal zero) ----------------
__global__ __launch_bounds__(256) void k_gatherln(const float* __restrict__ X, const float* __restrict__ g,
    const float* __restrict__ bb, const int* __restrict__ ti, const int* __restrict__ tj,
    float* __restrict__ Xnew, float* __restrict__ Xold, float* __restrict__ psal) {
  int b = blockIdx.y, p = blockIdx.x >> 1, side = blockIdx.x & 1;
  int tid = threadIdx.x, lane = tid & 63, w = tid >> 6;
  if (blockIdx.x == 0 && tid < TK) psal[b * TK + tid] = 0.f;
  int row = side ? tj[b * TK + p] : ti[b * TK + p];
  row = min(max(row, 0), Tq - 1);
  const float* xr = X + ((size_t)(b * Tq + row)) * Dq;
  float* dst = (side ? Xold : Xnew) + ((size_t)(b * TK + p)) * Dq;
  float4 a = *(const float4*)&xr[tid * 8];
  float4 c = *(const float4*)&xr[tid * 8 + 4];
  float s = a.x + a.y + a.z + a.w + c.x + c.y + c.z + c.w;
  float q = a.x*a.x + a.y*a.y + a.z*a.z + a.w*a.w + c.x*c.x + c.y*c.y + c.z*c.z + c.w*c.w;
  #pragma unroll
  for (int o = 32; o; o >>= 1) { s += __shfl_xor(s, o); q += __shfl_xor(q, o); }
  __shared__ float red[8];
  if (lane == 0) { red[w] = s; red[w + 4] = q; }
  __syncthreads();
  float S = red[0] + red[1] + red[2] + red[3];
  float Q = red[4] + red[5] + red[6] + red[7];
  float mean = S * (1.0f / Dq);
  float var = Q * (1.0f / Dq) - mean * mean;
  float rstd = rsqrtf(var + 1e-5f);
  float v[8] = {a.x, a.y, a.z, a.w, c.x, c.y, c.z, c.w};
  float o8[8];
  #pragma unroll
  for (int j = 0; j < 8; ++j) {
    int d = tid * 8 + j;
    o8[j] = (v[j] - mean) * rstd * g[d] + bb[d];
  }
  float4 s0; s0.x = o8[0]; s0.y = o8[1]; s0.z = o8[2]; s0.w = o8[3];
  float4 s1; s1.x = o8[4]; s1.y = o8[5]; s1.z = o8[6]; s1.w = o8[7];
  *(float4*)&dst[tid * 8] = s0;
  *(float4*)&dst[tid * 8 + 4] = s1;
}

// ---------------- exact pair_sal v3 ----------------
__global__ __launch_bounds__(256) void k_pairsal(const float* __restrict__ W0, const float* __restrict__ Xnew,
                                                 const float* __restrict__ Xold, float* __restrict__ psal) {
  int d0 = blockIdx.x * 64, e0 = blockIdx.y * 64;
  int tid = threadIdx.x, P = tid & 63, dg = tid >> 6;
  f32x4 xo[16];
  #pragma unroll
  for (int i = 0; i < 16; ++i)
    xo[i] = *(const f32x4*)&Xold[(size_t)P * Dq + e0 + i * 4];
  int dbase = d0 + dg * 16;
  f32x4 xn[4];
  #pragma unroll
  for (int i = 0; i < 4; ++i)
    xn[i] = *(const f32x4*)&Xnew[(size_t)P * Dq + dbase + i * 4];
  float acc = 0.f;
  #pragma unroll
  for (int dd = 0; dd < 16; ++dd) {
    int d = __builtin_amdgcn_readfirstlane(dbase + dd);
    const float* wr = W0 + (size_t)d * Dq + e0;
    float i0 = 0.f, i1 = 0.f, i2 = 0.f, i3 = 0.f;
    #pragma unroll
    for (int i = 0; i < 16; ++i) {
      float4 wv = *(const float4*)&wr[i * 4];
      i0 += wv.x * xo[i][0]; i1 += wv.y * xo[i][1];
      i2 += wv.z * xo[i][2]; i3 += wv.w * xo[i][3];
    }
    acc += xn[dd >> 2][dd & 3] * ((i0 + i1) + (i2 + i3));
  }
  __shared__ float part[4][64];
  part[dg][P] = acc;
  __syncthreads();
  if (tid < 64)
    atomicAdd(&psal[tid], part[0][tid] + part[1][tid] + part[2][tid] + part[3][tid]);
}

// ---------------- alpha softmax + R_t ----------------
__global__ __launch_bounds__(256) void k_alphart(const float* __restrict__ psal, const float* __restrict__ Xnew,
    const float* __restrict__ Xold, const float* __restrict__ Wv, float* __restrict__ Rt) {
  int bx = blockIdx.x, b = blockIdx.y;
  int tid = threadIdx.x, lane = tid & 63, w = tid >> 6;
  __shared__ float al[16], xd[Dq];
  if (tid == 0) {
    float mx = NEG_INF;
    #pragma unroll
    for (int p = 0; p < 16; ++p) mx = fmaxf(mx, psal[b * 16 + p]);
    float ee[16]; float s = 0.f;
    #pragma unroll
    for (int p = 0; p < 16; ++p) { ee[p] = expf(psal[b * 16 + p] - mx); s += ee[p]; }
    #pragma unroll
    for (int p = 0; p < 16; ++p) al[p] = ee[p] / s;
  }
  __syncthreads();
  {
    int d0 = tid * 8;
    float a8[8] = {0, 0, 0, 0, 0, 0, 0, 0};
    #pragma unroll
    for (int p = 0; p < 16; ++p) {
      const float* xn = Xnew + (size_t)(b * 16 + p) * Dq + d0;
      const float* xo = Xold + (size_t)(b * 16 + p) * Dq + d0;
      float ap = al[p];
      float4 n0 = *(const float4*)xn;
      float4 n1 = *(const float4*)(xn + 4);
      float4 o0 = *(const float4*)xo;
      float4 o1 = *(const float4*)(xo + 4);
      a8[0] += ap * (n0.x - o0.x); a8[1] += ap * (n0.y - o0.y);
      a8[2] += ap * (n0.z - o0.z); a8[3] += ap * (n0.w - o0.w);
      a8[4] += ap * (n1.x - o1.x); a8[5] += ap * (n1.y - o1.y);
      a8[6] += ap * (n1.z - o1.z); a8[7] += ap * (n1.w - o1.w);
    }
    #pragma unroll
    for (int j = 0; j < 8; ++j) xd[d0 + j] = a8[j];
  }
  __syncthreads();
  int e = bx * 4 + w;
  const float* wr = Wv + (size_t)e * Dq;
  float s = 0.f;
  #pragma unroll 8
  for (int d = lane; d < Dq; d += 64) s += wr[d] * xd[d];
  #pragma unroll
  for (int o = 32; o; o >>= 1) s += __shfl_xor(s, o);
  if (lane == 0) Rt[b * DB + e] = s;
}

// ---------------- slots stage A: sk row + compat  (grid K x B) ----------------
__global__ __launch_bounds__(256) void ksl_a(const float* __restrict__ slots, const float* __restrict__ Wk,
    const float* __restrict__ skb, const float* __restrict__ Rt, const float* __restrict__ temps,
    float* __restrict__ compat) {
  int k = blockIdx.x, b = blockIdx.y;
  int tid = threadIdx.x, g = tid >> 4, sub = tid & 15;
  __shared__ float s_s[DB], r_s[DB], sk_s[DB];
  if (tid < DB) { s_s[tid] = slots[((size_t)(b * Kq + k)) * DB + tid]; r_s[tid] = Rt[b * DB + tid]; }
  __syncthreads();
  #pragma unroll
  for (int r = 0; r < 8; ++r) {
    int e = g * 8 + r;
    const float* wr = Wk + e * DB;
    float a = 0.f;
    #pragma unroll
    for (int j = 0; j < 8; ++j) a += wr[sub + j * 16] * s_s[sub + j * 16];
    a += __shfl_xor(a, 8); a += __shfl_xor(a, 4); a += __shfl_xor(a, 2); a += __shfl_xor(a, 1);
    if (sub == 0) sk_s[e] = a + skb[k * DB + e];
  }
  __syncthreads();
  if (tid < 64) {
    float a = sk_s[tid] * r_s[tid] + sk_s[tid + 64] * r_s[tid + 64];
    #pragma unroll
    for (int o = 32; o; o >>= 1) a += __shfl_xor(a, o);
    if (tid == 0) {
      float t = temps[k];
      compat[b * Kq + k] = a * SD * log1pf(expf(t));
    }
  }
}

// ---------------- slots stage C: inline softmax + gate + su + LN + qkv (grid K x B) ----------------
__global__ __launch_bounds__(256) void ksl_c(const float* __restrict__ slots, const float* __restrict__ Rt,
    const float* __restrict__ compat, const float* __restrict__ Wgw, const float* __restrict__ Wgb,
    const float* __restrict__ lng, const float* __restrict__ lnb,
    const float* __restrict__ Wsq, const float* __restrict__ Wsk, const float* __restrict__ Wsv,
    float* __restrict__ suOut, float* __restrict__ qqOut, float* __restrict__ kkOut,
    float* __restrict__ vvOut) {
  int k = blockIdx.x, b = blockIdx.y;
  int tid = threadIdx.x, g = tid >> 4, sub = tid & 15;
  __shared__ float s_s[DB], r_s[DB], su[DB], bnl[DB];
  __shared__ float mvm, mvr;
  if (tid < DB) { s_s[tid] = slots[((size_t)(b * Kq + k)) * DB + tid]; r_s[tid] = Rt[b * DB + tid]; }
  __syncthreads();
  float swk;
  {
    float cm[Kq]; float mx = NEG_INF;
    #pragma unroll
    for (int kk = 0; kk < Kq; ++kk) { cm[kk] = compat[b * Kq + kk]; mx = fmaxf(mx, cm[kk]); }
    float ssum = 0.f;
    #pragma unroll
    for (int kk = 0; kk < Kq; ++kk) { cm[kk] = expf(cm[kk] - mx); ssum += cm[kk]; }
    swk = cm[k] / ssum;
  }
  #pragma unroll
  for (int r = 0; r < 8; ++r) {
    int e = g * 8 + r;
    const float* wr = Wgw + e * 256;
    float a = 0.f;
    #pragma unroll
    for (int j = 0; j < 16; ++j) {
      int col = sub + j * 16;
      float x = (j < 8) ? s_s[col] : swk * r_s[col - 128];
      a += wr[col] * x;
    }
    a += __shfl_xor(a, 8); a += __shfl_xor(a, 4); a += __shfl_xor(a, 2); a += __shfl_xor(a, 1);
    if (sub == 0) {
      a += Wgb[e];
      float gv = 1.0f / (1.0f + expf(-a));
      float wrv = swk * r_s[e];
      su[e] = (1.0f - gv) * s_s[e] + gv * wrv;
    }
  }
  __syncthreads();
  if (tid < 64) {
    float v0 = su[tid], v1 = su[tid + 64];
    float s = v0 + v1, q = v0 * v0 + v1 * v1;
    #pragma unroll
    for (int o = 32; o; o >>= 1) { s += __shfl_xor(s, o); q += __shfl_xor(q, o); }
    if (tid == 0) {
      float m = s / DB; float va = q / DB - m * m;
      mvm = m; mvr = rsqrtf(va + 1e-5f);
    }
  }
  __syncthreads();
  if (tid < DB) {
    bnl[tid] = (su[tid] - mvm) * mvr * lng[tid] + lnb[tid];
    suOut[((size_t)(b * Kq + k)) * DB + tid] = su[tid];
  }
  __syncthreads();
  #pragma unroll
  for (int r = 0; r < 8; ++r) {
    int e = g * 8 + r;
    const float* wr1 = Wsq + e * DB;
    const float* wr2 = Wsk + e * DB;
    const float* wr3 = Wsv + e * DB;
    float a1 = 0.f, a2 = 0.f, a3 = 0.f;
    #pragma unroll
    for (int j = 0; j < 8; ++j) {
      float x = bnl[sub + j * 16];
      a1 += wr1[sub + j * 16] * x;
      a2 += wr2[sub + j * 16] * x;
      a3 += wr3[sub + j * 16] * x;
    }
    #pragma unroll
    for (int o = 8; o; o >>= 1) {
      a1 += __shfl_xor(a1, o); a2 += __shfl_xor(a2, o); a3 += __shfl_xor(a3, o);
    }
    if (sub == 0) {
      size_t oi = ((size_t)(b * Kq + k)) * DB + e;
      qqOut[oi] = a1; kkOut[oi] = a2; vvOut[oi] = a3;
    }
  }
}

// ---------------- slots stage D: att + ctx + sn + kr (grid K x B) ----------------
__global__ __launch_bounds__(256) void ksl_d(const float* __restrict__ suOut, const float* __restrict__ qqOut,
    const float* __restrict__ kkOut, const float* __restrict__ vvOut, const float* __restrict__ lam,
    const float* __restrict__ Wkr, float* __restrict__ snOut, float* __restrict__ krOut) {
  int k = blockIdx.x, b = blockIdx.y;
  int tid = threadIdx.x, g = tid >> 4, sub = tid & 15;
  __shared__ float qq[DB], kks[Kq][DB], vvs[Kq][DB], att[8], sn_s[DB];
  if (tid < DB) qq[tid] = qqOut[((size_t)(b * Kq + k)) * DB + tid];
  for (int i = tid; i < Kq * DB; i += 256) {
    ((float*)kks)[i] = kkOut[(size_t)b * Kq * DB + i];
    ((float*)vvs)[i] = vvOut[(size_t)b * Kq * DB + i];
  }
  __syncthreads();
  if (tid < 112) {
    int m = g;
    float a = 0.f;
    #pragma unroll
    for (int j = 0; j < 8; ++j) a += qq[sub + j * 16] * kks[m][sub + j * 16];
    a += __shfl_xor(a, 8); a += __shfl_xor(a, 4); a += __shfl_xor(a, 2); a += __shfl_xor(a, 1);
    if (sub == 0) att[m] = a * SD;
  }
  __syncthreads();
  if (tid == 0) {
    float mx = att[0];
    for (int m = 1; m < Kq; ++m) mx = fmaxf(mx, att[m]);
    float s = 0.f;
    for (int m = 0; m < Kq; ++m) { att[m] = expf(att[m] - mx); s += att[m]; }
    for (int m = 0; m < Kq; ++m) att[m] /= s;
  }
  __syncthreads();
  if (tid < DB) {
    float c = 0.f;
    #pragma unroll
    for (int m = 0; m < Kq; ++m) c += att[m] * vvs[m][tid];
    float l = tanhf(lam[tid]); l = fminf(fmaxf(l, -1.0f), 1.0f);
    float v = suOut[((size_t)(b * Kq + k)) * DB + tid] + c * l;
    sn_s[tid] = v;
    snOut[((size_t)(b * Kq + k)) * DB + tid] = v;
  }
  __syncthreads();
  #pragma unroll
  for (int r = 0; r < 8; ++r) {
    int e = g * 8 + r;
    const float* wr = Wkr + e * DB;
    float a = 0.f;
    #pragma unroll
    for (int j = 0; j < 8; ++j) a += wr[sub + j * 16] * sn_s[sub + j * 16];
    a += __shfl_xor(a, 8); a += __shfl_xor(a, 4); a += __shfl_xor(a, 2); a += __shfl_xor(a, 1);
    if (sub == 0) krOut[((size_t)(b * Kq + k)) * DB + e] = a;
  }
}

// ---------------- M/Vg (bx<8) + aux losses (bx==8, b==0) ----------------
__global__ __launch_bounds__(256) void k_mvg(const float* __restrict__ snOut, const float* __restrict__ krOut,
    const float* __restrict__ Wqr, const float* __restrict__ Wvr, const float* __restrict__ rc,
    const float* __restrict__ basis, const float* __restrict__ slots,
    u16* __restrict__ Mb, u16* __restrict__ Vgb, float* __restrict__ out2) {
  int b = blockIdx.y, tid = threadIdx.x;
  if (blockIdx.x == 8) {
    if (b != 0) return;
    __shared__ float red[256];
    __shared__ float nrm[28];
    float p = 0.f;
    for (int i = tid; i < Bq * Kq * DB; i += 256) { float d = snOut[i] - slots[i]; p += d * d; }
    red[tid] = p; __syncthreads();
    for (int st = 128; st; st >>= 1) { if (tid < st) red[tid] += red[tid + st]; __syncthreads(); }
    if (tid == 0) out2[0] = red[0] / (float)(Bq * Kq * DB);
    if (tid < 28) {
      int bb2 = tid / 7, k = tid % 7;
      float s = 0.f;
      for (int e = 0; e < DB; ++e) { float v = snOut[(size_t)(bb2 * 7 + k) * DB + e]; s += v * v; }
      nrm[tid] = fmaxf(sqrtf(s), 1e-12f);
    }
    __syncthreads();
    float dv = 0.f;
    if (tid < 168) {
      int bb2 = tid / 42, r = tid % 42;
      int k = r / 6, m = r % 6; m += (m >= k);
      float dot = 0.f;
      for (int e = 0; e < DB; ++e)
        dot += snOut[(size_t)(bb2 * 7 + k) * DB + e] * snOut[(size_t)(bb2 * 7 + m) * DB + e];
      float c = dot / (nrm[bb2 * 7 + k] * nrm[bb2 * 7 + m]);
      dv = c * c;
    }
    red[tid] = dv; __syncthreads();
    for (int st = 128; st; st >>= 1) { if (tid < st) red[tid] += red[tid + st]; __syncthreads(); }
    if (tid == 0) out2[1] = red[0] / 168.0f;
    return;
  }
  int d = blockIdx.x * 256 + tid;
  __shared__ float krs[Kq][DB], sns[Kq][DB];
  for (int i = tid; i < Kq * DB; i += 256) {
    ((float*)krs)[i] = krOut[(size_t)b * Kq * DB + i];
    ((float*)sns)[i] = snOut[(size_t)b * Kq * DB + i];
  }
  __syncthreads();
  float b0 = basis[b * 3 + 0], b1 = basis[b * 3 + 1], b2 = basis[b * 3 + 2];
  float am[7] = {0, 0, 0, 0, 0, 0, 0};
  for (int e = 0; e < DB; ++e) {
    float wq = Wqr[(size_t)e * Dq + d];
    #pragma unroll
    for (int k = 0; k < 7; ++k) am[k] += krs[k][e] * wq;
  }
  float vr[7] = {0, 0, 0, 0, 0, 0, 0};
  const float* wvrow = Wvr + (size_t)d * DB;
  for (int e = 0; e < DB; ++e) {
    float wv = wvrow[e];
    #pragma unroll
    for (int k = 0; k < 7; ++k) vr[k] += sns[k][e] * wv;
  }
  #pragma unroll
  for (int k = 0; k < 7; ++k) {
    Mb[((size_t)b * 7 + k) * Dq + d] = f2bf(am[k]);
    float gt = tanhf(b0 * rc[((size_t)k * 3 + 0) * Dq + d] +
                     b1 * rc[((size_t)k * 3 + 1) * Dq + d] +
                     b2 * rc[((size_t)k * 3 + 2) * Dq + d]);
    gt = fminf(fmaxf(gt, -1.0f), 1.0f);
    Vgb[((size_t)b * 7 + k) * Dq + d] = f2bf(vr[k] * gt);
  }
}

// ---------------- final render read: direct L2 reads ----------------
__global__ __launch_bounds__(256) void k_z(const float* __restrict__ X, const u16* __restrict__ Mb,
                                           const u16* __restrict__ Vgb, float* __restrict__ Z) {
  int b = blockIdx.y, t0 = blockIdx.x * 16;
  int tid = threadIdx.x, lane = tid & 63, w = tid >> 6;
  const u16* Ms = Mb + (size_t)b * 7 * 2048;
  const u16* Vs = Vgb + (size_t)b * 7 * 2048;
  for (int ri = 0; ri < 4; ++ri) {
    int t = t0 + ri * 4 + w;
    const float* xr = X + ((size_t)b * Tq + t) * Dq;
    float sc[7] = {0, 0, 0, 0, 0, 0, 0};
    #pragma unroll
    for (int i = 0; i < 8; ++i) {
      int d = lane * 4 + i * 256;
      float4 x = *(const float4*)&xr[d];
      #pragma unroll
      for (int k = 0; k < 7; ++k) {
        uint2 mm = *(const uint2*)&Ms[k * 2048 + d];
        sc[k] += x.x * bfbits2f(mm.x & 0xffffu) + x.y * bfbits2f(mm.x >> 16)
               + x.z * bfbits2f(mm.y & 0xffffu) + x.w * bfbits2f(mm.y >> 16);
      }
    }
    #pragma unroll
    for (int k = 0; k < 7; ++k) {
      #pragma unroll
      for (int o = 32; o; o >>= 1) sc[k] += __shfl_xor(sc[k], o);
    }
    float mx = sc[0];
    #pragma unroll
    for (int k = 1; k < 7; ++k) mx = fmaxf(mx, sc[k]);
    float pz[7]; float s = 0.f;
    #pragma unroll
    for (int k = 0; k < 7; ++k) { pz[k] = expf((sc[k] - mx) * SD); s += pz[k]; }
    float inv = 1.0f / s;
    #pragma unroll
    for (int k = 0; k < 7; ++k) pz[k] *= inv;
    float* zr = Z + ((size_t)b * Tq + t) * Dq;
    #pragma unroll
    for (int i = 0; i < 8; ++i) {
      int d = lane * 4 + i * 256;
      float4 o4; o4.x = o4.y = o4.z = o4.w = 0.f;
      #pragma unroll
      for (int k = 0; k < 7; ++k) {
        uint2 vm = *(const uint2*)&Vs[k * 2048 + d];
        float pk = pz[k];
        o4.x += pk * bfbits2f(vm.x & 0xffffu); o4.y += pk * bfbits2f(vm.x >> 16);
        o4.z += pk * bfbits2f(vm.y & 0xffffu); o4.w += pk * bfbits2f(vm.y >> 16);
      }
      *(float4*)&zr[d] = o4;
    }
  }
}

extern "C" void kernel_launch(void* const* d_in, const int* in_sizes, int n_in,
                              void* d_out, int out_size, void* d_ws, size_t ws_size,
                              hipStream_t stream) {
  const float* Xw   = (const float*)d_in[0];
  const float* Xr   = (const float*)d_in[1];
  const float* slots= (const float*)d_in[2];
  const float* W0   = (const float*)d_in[3];
  const float* lng  = (const float*)d_in[4];
  const float* lnb  = (const float*)d_in[5];
  const float* Wv   = (const float*)d_in[6];
  const float* Wk   = (const float*)d_in[7];
  const float* skb  = (const float*)d_in[8];
  const float* Wgw  = (const float*)d_in[9];
  const float* Wgb  = (const float*)d_in[10];
  const float* lsg  = (const float*)d_in[11];
  const float* lsb  = (const float*)d_in[12];
  const float* Wsq  = (const float*)d_in[13];
  const float* Wsk  = (const float*)d_in[14];
  const float* Wsv  = (const float*)d_in[15];
  const float* lam  = (const float*)d_in[16];
  const float* Wqr  = (const float*)d_in[17];
  const float* Wkr  = (const float*)d_in[18];
  const float* Wvr  = (const float*)d_in[19];
  const float* rc   = (const float*)d_in[20];
  const float* temps= (const float*)d_in[21];

  char* wsb = (char*)d_ws;
  size_t off = 0;
  auto alloc = [&](size_t bytes) -> void* {
    void* p = wsb + off;
    off += (bytes + 255) & ~(size_t)255;
    return p;
  };
  u16*   Xn   = (u16*)  alloc((size_t)Bq * Tq * Dq * 2);
  u16*   XW0  = (u16*)  alloc((size_t)Bq * Tq * Dq * 2);
  u16*   W0b  = (u16*)  alloc((size_t)Dq * Dq * 2);
  float* sal  = (float*)alloc((size_t)Bq * Tq * 64 * 4);
  int*   ti   = (int*)  alloc(Bq * TK * 4);
  int*   tj   = (int*)  alloc(Bq * TK * 4);
  float* Xnew = (float*)alloc((size_t)Bq * TK * Dq * 4);
  float* Xold = (float*)alloc((size_t)Bq * TK * Dq * 4);
  float* psal = (float*)alloc(Bq * TK * 4);
  float* Rt   = (float*)alloc(Bq * DB * 4);
  float* qm   = (float*)alloc(Bq * Dq * 4);
  float* w0q  = (float*)alloc(Bq * Dq * 4);
  float* basis= (float*)alloc(Bq * 3 * 4);
  float* krOut= (float*)alloc(Bq * Kq * DB * 4);
  u16*   Mbf  = (u16*)  alloc((size_t)Bq * Kq * Dq * 2);
  u16*   Vgb  = (u16*)  alloc((size_t)Bq * Kq * Dq * 2);
  float* cv   = (float*)alloc((size_t)Bq * 128 * 16 * 4);
  int*   ci   = (int*)  alloc((size_t)Bq * 128 * 16 * 4);
  float* part = (float*)alloc((size_t)Bq * 32 * Dq * 4);
  float* compat = (float*)alloc(Bq * Kq * 4);
  float* suB  = (float*)alloc(Bq * Kq * DB * 4);
  float* qqB  = (float*)alloc(Bq * Kq * DB * 4);
  float* kkB  = (float*)alloc(Bq * Kq * DB * 4);
  float* vvB  = (float*)alloc(Bq * Kq * DB * 4);

  float* Zout = (float*)d_out;
  float* snOut = Zout + (size_t)Bq * Tq * Dq;
  float* lossOut = snOut + Bq * Kq * DB;

  k_prep  <<<2048 + 8192 + 256, 256, 0, stream>>>(W0, W0b, Xw, lng, lnb, Xn, Xr, part);
  k_gemm  <<<dim3(64, 17), 256, 0, stream>>>(Xn, W0b, XW0, Bq * Tq, Dq, Dq, part, qm);
  k_band  <<<dim3(64, Bq + 1), 768, 0, stream>>>(Xn, XW0, sal, W0, qm, w0q);
  k_topk1 <<<dim3(129, Bq), 256, 0, stream>>>(sal, cv, ci, qm, w0q, basis);
  k_topk2 <<<Bq, 256, 0, stream>>>(cv, ci, ti, tj);
  k_gatherln<<<dim3(32, Bq), 256, 0, stream>>>(Xw, lng, lnb, ti, tj, Xnew, Xold, psal);
  k_pairsal<<<dim3(32, 32), 256, 0, stream>>>(W0, Xnew, Xold, psal);
  k_alphart<<<dim3(32, Bq), 256, 0, stream>>>(psal, Xnew, Xold, Wv, Rt);
  ksl_a   <<<dim3(Kq, Bq), 256, 0, stream>>>(slots, Wk, skb, Rt, temps, compat);
  ksl_c   <<<dim3(Kq, Bq), 256, 0, stream>>>(slots, Rt, compat, Wgw, Wgb, lsg, lsb,
                                             Wsq, Wsk, Wsv, suB, qqB, kkB, vvB);
  ksl_d   <<<dim3(Kq, Bq), 256, 0, stream>>>(suB, qqB, kkB, vvB, lam, Wkr, snOut, krOut);
  k_mvg   <<<dim3(9, Bq), 256, 0, stream>>>(snOut, krOut, Wqr, Wvr, rc, basis, slots,
                                            Mbf, Vgb, lossOut);
  k_z     <<<dim3(128, Bq), 256, 0, stream>>>(Xr, Mbf, Vgb, Zout);
}